// Round 6
// baseline (784.486 us; speedup 1.0000x reference)
//
#include <hip/hip_runtime.h>
#include <stdint.h>

// d_out (f32) layout: seed [64][3][256] @0, x3 [64][128][256] @49152,
// fps x [64][3][512] @2146304.  x3 region doubles as x1 staging.
#define X3_OFF 49152
#define FPS_OFF 2146304

// ws (f32) layout: T1 @0, T1s @8192, T3 @16384, T3s @24576 (each [128][64]),
// featT [512][64] @32768.  Total 65536 floats = 256 KB.

typedef float v2f __attribute__((ext_vector_type(2)));

// ---------------------------------------------------------------------------
// k_prep: featT[c][b] = feat[b][c]
// ---------------------------------------------------------------------------
__global__ void k_prep(const float* __restrict__ feat, float* __restrict__ ws) {
    int g = blockIdx.x * 256 + threadIdx.x;   // 32768
    int c = g >> 6, b = g & 63;
    ws[32768 + c * 64 + b] = feat[b * 512 + c];
}

// ---------------------------------------------------------------------------
// k_tterms: T[o][b] = sum_c W[o][128+c] * feat[b][c] for the 4 concat weights
// unroll 4: 0.5 block/CU -> latency-bound; keep more W/ft loads in flight.
// ---------------------------------------------------------------------------
__global__ void k_tterms(const float* __restrict__ w1, const float* __restrict__ ws1,
                         const float* __restrict__ w3, const float* __restrict__ ws3,
                         float* __restrict__ ws) {
    int g = blockIdx.x * 256 + threadIdx.x;   // 32768
    int which = g >> 13;
    int o = (g >> 6) & 127;
    int b = g & 63;
    const float* W = (which == 0) ? w1 : (which == 1) ? ws1
                     : (which == 2) ? w3 : ws3;
    const float* ft = ws + 32768;
    float acc = 0.f;
#pragma unroll 4
    for (int c = 0; c < 512; ++c)
        acc = fmaf(W[o * 640 + 128 + c], ft[c * 64 + b], acc);
    ws[which * 8192 + o * 64 + b] = acc;
}

// ---------------------------------------------------------------------------
// k_deconv (R6-proven): x1[b][o][k] = sum_c feat[b][c]*ps_w[c][o][k] + ps_b[o]
// acc[16], y-blocks=4.  // acc[32] variant spilled (R7: no launch_bounds)
// ---------------------------------------------------------------------------
__global__ void k_deconv(const float* __restrict__ psw,
                         const float* __restrict__ psb,
                         const float* __restrict__ ws,
                         float* __restrict__ stage) {
    int n = blockIdx.x * 256 + threadIdx.x;   // 32768 = o*256+k
    int b0 = blockIdx.y * 16;
    const float* featT = ws + 32768;
    float acc[16];
    float bias = psb[n >> 8];
#pragma unroll
    for (int j = 0; j < 16; ++j) acc[j] = bias;
    for (int c = 0; c < 512; ++c) {
        float pw = psw[c * 32768 + n];
#pragma unroll
        for (int j = 0; j < 16; ++j)
            acc[j] = fmaf(pw, featT[c * 64 + b0 + j], acc[j]);
    }
#pragma unroll
    for (int j = 0; j < 16; ++j)
        stage[(b0 + j) * 32768 + n] = acc[j];
}

// ---------------------------------------------------------------------------
// gemm8: acc[r] += sum_i S[i][lane] * Wg[(o0+r)*ld + i]  (o0 wave-uniform)
// ---------------------------------------------------------------------------
__device__ __forceinline__ void gemm8(const float* __restrict__ Wg, int ld, int o0,
                                      const float* S, int K, float acc[8], int lane) {
#pragma unroll 4
    for (int i = 0; i < K; ++i) {
        float x = S[i * 64 + lane];
#pragma unroll
        for (int r = 0; r < 8; ++r)
            acc[r] = fmaf(x, Wg[(o0 + r) * ld + i], acc[r]);
    }
}

// ---------------------------------------------------------------------------
// k_fused: per (b, 64-wide k-tile): x1 -> m1 -> m2 -> m3 -> m4/seed.
// ---------------------------------------------------------------------------
struct FusedW {
    const float *m1_w1, *m1_b1, *m1_w2, *m1_b2, *m1_ws, *m1_bs;
    const float *m2_w1, *m2_b1, *m2_w2, *m2_b2, *m2_ws, *m2_bs;
    const float *m3_w1, *m3_b1, *m3_w2, *m3_b2, *m3_ws, *m3_bs;
    const float *m4_w1, *m4_b1, *m4_w2, *m4_b2;
};

__global__ void __launch_bounds__(512)
k_fused(FusedW P, const float* __restrict__ ws, float* __restrict__ fout) {
    int b  = blockIdx.x >> 2;
    int k0 = (blockIdx.x & 3) * 64;
    int lane = threadIdx.x & 63;
    int wave = __builtin_amdgcn_readfirstlane(threadIdx.x >> 6);

    const float* T1  = ws;
    const float* T1s = ws + 8192;
    const float* T3  = ws + 16384;
    const float* T3s = ws + 24576;
    float* stage = fout + X3_OFF + b * 32768;

    __shared__ float Xs[8192];
    __shared__ float Hs[8192];

#pragma unroll
    for (int s = 0; s < 16; ++s) {
        int e = threadIdx.x + s * 512;
        int o = e >> 6, kk = e & 63;
        Xs[e] = stage[o * 256 + k0 + kk];
    }
    __syncthreads();

    float yreg[2][8];

    // ================= m1 =================
#pragma unroll
    for (int half = 0; half < 2; ++half) {
        int o0 = wave * 16 + half * 8;
        float acc[8];
#pragma unroll
        for (int r = 0; r < 8; ++r) acc[r] = T1[(o0 + r) * 64 + b] + P.m1_b1[o0 + r];
        gemm8(P.m1_w1, 640, o0, Xs, 128, acc, lane);
#pragma unroll
        for (int r = 0; r < 8; ++r) Hs[(o0 + r) * 64 + lane] = fmaxf(acc[r], 0.f);
    }
    __syncthreads();
#pragma unroll
    for (int half = 0; half < 2; ++half) {
        int o0 = wave * 16 + half * 8;
        float acc[8];
#pragma unroll
        for (int r = 0; r < 8; ++r)
            acc[r] = T1s[(o0 + r) * 64 + b] + P.m1_b2[o0 + r] + P.m1_bs[o0 + r];
        gemm8(P.m1_w2, 128, o0, Hs, 128, acc, lane);
        gemm8(P.m1_ws, 640, o0, Xs, 128, acc, lane);
#pragma unroll
        for (int r = 0; r < 8; ++r) yreg[half][r] = acc[r];
    }
    __syncthreads();
#pragma unroll
    for (int half = 0; half < 2; ++half) {
        int o0 = wave * 16 + half * 8;
#pragma unroll
        for (int r = 0; r < 8; ++r) Xs[(o0 + r) * 64 + lane] = yreg[half][r];
    }
    __syncthreads();

    // ================= m2 =================
    {
        int o0 = wave * 8;
        float acc[8];
#pragma unroll
        for (int r = 0; r < 8; ++r) acc[r] = P.m2_b1[o0 + r];
        gemm8(P.m2_w1, 128, o0, Xs, 128, acc, lane);
#pragma unroll
        for (int r = 0; r < 8; ++r) Hs[(o0 + r) * 64 + lane] = fmaxf(acc[r], 0.f);
    }
    __syncthreads();
#pragma unroll
    for (int half = 0; half < 2; ++half) {
        int o0 = wave * 16 + half * 8;
        float acc[8];
#pragma unroll
        for (int r = 0; r < 8; ++r) acc[r] = P.m2_b2[o0 + r] + P.m2_bs[o0 + r];
        gemm8(P.m2_w2, 64, o0, Hs, 64, acc, lane);
        gemm8(P.m2_ws, 128, o0, Xs, 128, acc, lane);
#pragma unroll
        for (int r = 0; r < 8; ++r) yreg[half][r] = acc[r];
    }
    __syncthreads();
#pragma unroll
    for (int half = 0; half < 2; ++half) {
        int o0 = wave * 16 + half * 8;
#pragma unroll
        for (int r = 0; r < 8; ++r) Xs[(o0 + r) * 64 + lane] = yreg[half][r];
    }
    __syncthreads();

    // ================= m3 =================
#pragma unroll
    for (int half = 0; half < 2; ++half) {
        int o0 = wave * 16 + half * 8;
        float acc[8];
#pragma unroll
        for (int r = 0; r < 8; ++r) acc[r] = T3[(o0 + r) * 64 + b] + P.m3_b1[o0 + r];
        gemm8(P.m3_w1, 640, o0, Xs, 128, acc, lane);
#pragma unroll
        for (int r = 0; r < 8; ++r) Hs[(o0 + r) * 64 + lane] = fmaxf(acc[r], 0.f);
    }
    __syncthreads();
#pragma unroll
    for (int half = 0; half < 2; ++half) {
        int o0 = wave * 16 + half * 8;
        float acc[8];
#pragma unroll
        for (int r = 0; r < 8; ++r)
            acc[r] = T3s[(o0 + r) * 64 + b] + P.m3_b2[o0 + r] + P.m3_bs[o0 + r];
        gemm8(P.m3_w2, 128, o0, Hs, 128, acc, lane);
        gemm8(P.m3_ws, 640, o0, Xs, 128, acc, lane);
#pragma unroll
        for (int r = 0; r < 8; ++r) yreg[half][r] = acc[r];
    }
    __syncthreads();
#pragma unroll
    for (int half = 0; half < 2; ++half) {
        int o0 = wave * 16 + half * 8;
#pragma unroll
        for (int r = 0; r < 8; ++r) {
            Xs[(o0 + r) * 64 + lane] = yreg[half][r];
            stage[(o0 + r) * 256 + k0 + lane] = yreg[half][r];
        }
    }
    __syncthreads();

    // ================= m4 / seed =================
    {
        int o0 = wave * 8;
        float acc[8];
#pragma unroll
        for (int r = 0; r < 8; ++r) acc[r] = P.m4_b1[o0 + r];
        gemm8(P.m4_w1, 128, o0, Xs, 128, acc, lane);
#pragma unroll
        for (int r = 0; r < 8; ++r) Hs[(o0 + r) * 64 + lane] = fmaxf(acc[r], 0.f);
    }
    __syncthreads();
    if (wave < 3) {
        int d = wave;
        float s = P.m4_b2[d];
        for (int j = 0; j < 64; ++j)
            s = fmaf(Hs[j * 64 + lane], P.m4_w2[d * 64 + j], s);
        fout[b * 768 + d * 256 + k0 + lane] = s;
    }
}

// ---------------------------------------------------------------------------
// DPP wave-64 reductions (canonical GCN pattern: row_shr 1/2/4/8 +
// row_bcast15 (rows 1,3) + row_bcast31 (rows 2,3)); result in lane 63.
// Identity-old makes masked/invalid lanes no-ops.  (v4-proven: fuse to
// v_max_u32_dpp / v_min_u32_dpp — 1 instr per step.)
// ---------------------------------------------------------------------------
__device__ __forceinline__ unsigned wave_max_u32_l63(unsigned v) {
    unsigned t;
    t = (unsigned)__builtin_amdgcn_update_dpp(0, (int)v, 0x111, 0xf, 0xf, false); v = t > v ? t : v;
    t = (unsigned)__builtin_amdgcn_update_dpp(0, (int)v, 0x112, 0xf, 0xf, false); v = t > v ? t : v;
    t = (unsigned)__builtin_amdgcn_update_dpp(0, (int)v, 0x114, 0xf, 0xf, false); v = t > v ? t : v;
    t = (unsigned)__builtin_amdgcn_update_dpp(0, (int)v, 0x118, 0xf, 0xf, false); v = t > v ? t : v;
    t = (unsigned)__builtin_amdgcn_update_dpp(0, (int)v, 0x142, 0xa, 0xf, false); v = t > v ? t : v;
    t = (unsigned)__builtin_amdgcn_update_dpp(0, (int)v, 0x143, 0xc, 0xf, false); v = t > v ? t : v;
    return v;
}
__device__ __forceinline__ unsigned wave_min_u32_l63(unsigned v) {
    unsigned t;
    t = (unsigned)__builtin_amdgcn_update_dpp(-1, (int)v, 0x111, 0xf, 0xf, false); v = t < v ? t : v;
    t = (unsigned)__builtin_amdgcn_update_dpp(-1, (int)v, 0x112, 0xf, 0xf, false); v = t < v ? t : v;
    t = (unsigned)__builtin_amdgcn_update_dpp(-1, (int)v, 0x114, 0xf, 0xf, false); v = t < v ? t : v;
    t = (unsigned)__builtin_amdgcn_update_dpp(-1, (int)v, 0x118, 0xf, 0xf, false); v = t < v ? t : v;
    t = (unsigned)__builtin_amdgcn_update_dpp(-1, (int)v, 0x142, 0xa, 0xf, false); v = t < v ? t : v;
    t = (unsigned)__builtin_amdgcn_update_dpp(-1, (int)v, 0x143, 0xc, 0xf, false); v = t < v ? t : v;
    return v;
}

// ---------------------------------------------------------------------------
// k_fps (v9 = v4 reduce structure + FORCED packed-f32 dist via inline asm).
// R4/R5 lesson: v4's reduce/merge is a local optimum; attack ISSUE count.
// v_pk_add_f32/v_pk_mul_f32 (VOP3P, CDNA) process 2 points per instr; the
// compiler never emits them from float2 source (R0/R1 neutral), so force
// via asm.  Bit-exactness: a-b == a+(-b) in IEEE (sign flip exact), pk ops
// are IEEE-rn per component, and the mul,mul,mul,add,add shape is kept (no
// fma contraction).  Scalar fminf (no pk_min_f32) + v4's exact serial
// chain / 2-phase fused-u32 DPP / u64-key merge / pts[bi] broadcast.
// ---------------------------------------------------------------------------
__global__ void __launch_bounds__(256)
k_fps(const float* __restrict__ seed, const float* __restrict__ partial,
      float* __restrict__ outx) {
    int b = blockIdx.x;
    int tid = threadIdx.x;        // 0..255
    int lane = tid & 63;
    int wv = tid >> 6;            // 0..3

    __shared__ float pts[4352 * 3];          // [idx][3]
    __shared__ unsigned long long cand[2][4];
    __shared__ int fars[512];

    // stage seed [b][3][256] -> pts[idx<256]
    pts[tid * 3 + 0] = seed[b * 768 + tid];
    pts[tid * 3 + 1] = seed[b * 768 + 256 + tid];
    pts[tid * 3 + 2] = seed[b * 768 + 512 + tid];
    // stage partial [b][4096][3] -> pts[256..4351]  (linear 12288 dwords)
#pragma unroll
    for (int j = 0; j < 48; ++j) {
        int e = tid + j * 256;
        pts[768 + e] = partial[b * 12288 + e];
    }
    if (tid == 0) fars[0] = 0;
    __syncthreads();

    // 17 pts/thread: 8 packed pairs (s=2k,2k+1) + scalar tail (s=16)
    v2f px2[8], py2[8], pz2[8];
#pragma unroll
    for (int k = 0; k < 8; ++k) {
        int g0 = (2 * k) * 256 + tid, g1 = g0 + 256;
        px2[k] = (v2f){pts[g0 * 3 + 0], pts[g1 * 3 + 0]};
        py2[k] = (v2f){pts[g0 * 3 + 1], pts[g1 * 3 + 1]};
        pz2[k] = (v2f){pts[g0 * 3 + 2], pts[g1 * 3 + 2]};
    }
    float pxt, pyt, pzt;
    {
        int g = 16 * 256 + tid;
        pxt = pts[g * 3 + 0]; pyt = pts[g * 3 + 1]; pzt = pts[g * 3 + 2];
    }
    float dist[17];
#pragma unroll
    for (int s = 0; s < 17; ++s) dist[s] = 1e10f;

    float cx = pts[0], cy = pts[1], cz = pts[2];

    for (int t = 0; t < 511; ++t) {
        // ---- dist update, packed: d = (p-c)x^2 + (p-c)y^2 + (p-c)z^2 ----
        v2f ncx = (v2f){-cx, -cx};
        v2f ncy = (v2f){-cy, -cy};
        v2f ncz = (v2f){-cz, -cz};
#pragma unroll
        for (int k = 0; k < 8; ++k) {
            v2f dx, dy, dz, xx, yy, zz, s01, dd;
            asm("v_pk_add_f32 %0, %1, %2" : "=v"(dx) : "v"(px2[k]), "v"(ncx));
            asm("v_pk_add_f32 %0, %1, %2" : "=v"(dy) : "v"(py2[k]), "v"(ncy));
            asm("v_pk_add_f32 %0, %1, %2" : "=v"(dz) : "v"(pz2[k]), "v"(ncz));
            asm("v_pk_mul_f32 %0, %1, %1" : "=v"(xx) : "v"(dx));
            asm("v_pk_mul_f32 %0, %1, %1" : "=v"(yy) : "v"(dy));
            asm("v_pk_mul_f32 %0, %1, %1" : "=v"(zz) : "v"(dz));
            asm("v_pk_add_f32 %0, %1, %2" : "=v"(s01) : "v"(xx), "v"(yy));
            asm("v_pk_add_f32 %0, %1, %2" : "=v"(dd) : "v"(s01), "v"(zz));
            dist[2 * k]     = fminf(dist[2 * k],     dd[0]);
            dist[2 * k + 1] = fminf(dist[2 * k + 1], dd[1]);
        }
        {   // tail s=16, scalar, bit-exact same shape
            float dx = pxt - cx, dy = pyt - cy, dz = pzt - cz;
            float d = __fadd_rn(__fadd_rn(__fmul_rn(dx, dx), __fmul_rn(dy, dy)),
                                __fmul_rn(dz, dz));
            dist[16] = fminf(dist[16], d);
        }
        // ---- v4 serial chain: ascending s, strict '>' (first-index ties) --
        float bv = -1.0f; int bg = 0;
#pragma unroll
        for (int s = 0; s < 17; ++s)
            if (dist[s] > bv) { bv = dist[s]; bg = s * 256 + tid; }
        // phase 1: wave max of dist bits (dist >= 0 so u32 order == f32 order)
        unsigned mv = wave_max_u32_l63(__float_as_uint(bv));
        unsigned maxbits = (unsigned)__builtin_amdgcn_readlane((int)mv, 63);
        // phase 2: wave min of candidate global index among exact-max ties
        unsigned cg = (__float_as_uint(bv) == maxbits) ? (unsigned)bg : 0xFFFFFFFFu;
        unsigned mgv = wave_min_u32_l63(cg);
        unsigned big = (unsigned)__builtin_amdgcn_readlane((int)mgv, 63);

        if (lane == 0)
            cand[t & 1][wv] = (((unsigned long long)maxbits) << 32) |
                              (unsigned long long)(8191u - big);
        __syncthreads();
        unsigned long long U0 = cand[t & 1][0];
        unsigned long long U1 = cand[t & 1][1];
        unsigned long long U2 = cand[t & 1][2];
        unsigned long long U3 = cand[t & 1][3];
        if (U1 > U0) U0 = U1;
        if (U3 > U2) U2 = U3;
        if (U2 > U0) U0 = U2;
        int bi = 8191 - (int)(U0 & 8191ull);
        cx = pts[bi * 3 + 0]; cy = pts[bi * 3 + 1]; cz = pts[bi * 3 + 2];
        if (tid == 0) fars[t + 1] = bi;
    }
    __syncthreads();

    // gather outputs: x [b][3][512]
#pragma unroll
    for (int j = 0; j < 2; ++j) {
        int n = tid + j * 256;
        int idx = fars[n];
        int ob = b * 1536 + n;
        outx[ob]        = pts[idx * 3 + 0];
        outx[ob + 512]  = pts[idx * 3 + 1];
        outx[ob + 1024] = pts[idx * 3 + 2];
    }
}

// ---------------------------------------------------------------------------
extern "C" void kernel_launch(void* const* d_in, const int* in_sizes, int n_in,
                              void* d_out, int out_size, void* d_ws, size_t ws_size,
                              hipStream_t stream) {
    (void)in_sizes; (void)n_in; (void)out_size; (void)ws_size;
    const float* feat    = (const float*)d_in[0];
    const float* partial = (const float*)d_in[3];
    const float* psw     = (const float*)d_in[4];
    const float* psb     = (const float*)d_in[5];

    FusedW P;
    P.m1_w1 = (const float*)d_in[6];  P.m1_b1 = (const float*)d_in[7];
    P.m1_w2 = (const float*)d_in[8];  P.m1_b2 = (const float*)d_in[9];
    P.m1_ws = (const float*)d_in[10]; P.m1_bs = (const float*)d_in[11];
    P.m2_w1 = (const float*)d_in[12]; P.m2_b1 = (const float*)d_in[13];
    P.m2_w2 = (const float*)d_in[14]; P.m2_b2 = (const float*)d_in[15];
    P.m2_ws = (const float*)d_in[16]; P.m2_bs = (const float*)d_in[17];
    P.m3_w1 = (const float*)d_in[18]; P.m3_b1 = (const float*)d_in[19];
    P.m3_w2 = (const float*)d_in[20]; P.m3_b2 = (const float*)d_in[21];
    P.m3_ws = (const float*)d_in[22]; P.m3_bs = (const float*)d_in[23];
    P.m4_w1 = (const float*)d_in[24]; P.m4_b1 = (const float*)d_in[25];
    P.m4_w2 = (const float*)d_in[26]; P.m4_b2 = (const float*)d_in[27];

    float* W = (float*)d_ws;
    float* out = (float*)d_out;

    k_prep<<<dim3(128), dim3(256), 0, stream>>>(feat, W);
    k_tterms<<<dim3(128), dim3(256), 0, stream>>>(P.m1_w1, P.m1_ws, P.m3_w1, P.m3_ws, W);
    k_deconv<<<dim3(128, 4), dim3(256), 0, stream>>>(psw, psb, W, out + X3_OFF);
    k_fused<<<dim3(256), dim3(512), 0, stream>>>(P, W, out);
    k_fps<<<dim3(64), dim3(256), 0, stream>>>(out, partial, out + FPS_OFF);
}

// Round 8
// 764.092 us; speedup vs baseline: 1.0267x; 1.0267x over previous
//
#include <hip/hip_runtime.h>
#include <stdint.h>

// d_out (f32) layout: seed [64][3][256] @0, x3 [64][128][256] @49152,
// fps x [64][3][512] @2146304.  x3 region doubles as x1 staging.
#define X3_OFF 49152
#define FPS_OFF 2146304

// ws (f32) layout: T1 @0, T1s @8192, T3 @16384, T3s @24576 (each [128][64]),
// featT [512][64] @32768.  Total 65536 floats = 256 KB.

// ---------------------------------------------------------------------------
// k_prep: featT[c][b] = feat[b][c]
// ---------------------------------------------------------------------------
__global__ void k_prep(const float* __restrict__ feat, float* __restrict__ ws) {
    int g = blockIdx.x * 256 + threadIdx.x;   // 32768
    int c = g >> 6, b = g & 63;
    ws[32768 + c * 64 + b] = feat[b * 512 + c];
}

// ---------------------------------------------------------------------------
// k_tterms: T[o][b] = sum_c W[o][128+c] * feat[b][c] for the 4 concat weights
// ---------------------------------------------------------------------------
__global__ void k_tterms(const float* __restrict__ w1, const float* __restrict__ ws1,
                         const float* __restrict__ w3, const float* __restrict__ ws3,
                         float* __restrict__ ws) {
    int g = blockIdx.x * 256 + threadIdx.x;   // 32768
    int which = g >> 13;
    int o = (g >> 6) & 127;
    int b = g & 63;
    const float* W = (which == 0) ? w1 : (which == 1) ? ws1
                     : (which == 2) ? w3 : ws3;
    const float* ft = ws + 32768;
    float acc = 0.f;
#pragma unroll 4
    for (int c = 0; c < 512; ++c)
        acc = fmaf(W[o * 640 + 128 + c], ft[c * 64 + b], acc);
    ws[which * 8192 + o * 64 + b] = acc;
}

// ---------------------------------------------------------------------------
// k_deconv (R6-proven): x1[b][o][k] = sum_c feat[b][c]*ps_w[c][o][k] + ps_b[o]
// acc[16], y-blocks=4.
// ---------------------------------------------------------------------------
__global__ void k_deconv(const float* __restrict__ psw,
                         const float* __restrict__ psb,
                         const float* __restrict__ ws,
                         float* __restrict__ stage) {
    int n = blockIdx.x * 256 + threadIdx.x;   // 32768 = o*256+k
    int b0 = blockIdx.y * 16;
    const float* featT = ws + 32768;
    float acc[16];
    float bias = psb[n >> 8];
#pragma unroll
    for (int j = 0; j < 16; ++j) acc[j] = bias;
    for (int c = 0; c < 512; ++c) {
        float pw = psw[c * 32768 + n];
#pragma unroll
        for (int j = 0; j < 16; ++j)
            acc[j] = fmaf(pw, featT[c * 64 + b0 + j], acc[j]);
    }
#pragma unroll
    for (int j = 0; j < 16; ++j)
        stage[(b0 + j) * 32768 + n] = acc[j];
}

// ---------------------------------------------------------------------------
// gemm8: acc[r] += sum_i S[i][lane] * Wg[(o0+r)*ld + i]  (o0 wave-uniform)
// ---------------------------------------------------------------------------
__device__ __forceinline__ void gemm8(const float* __restrict__ Wg, int ld, int o0,
                                      const float* S, int K, float acc[8], int lane) {
#pragma unroll 4
    for (int i = 0; i < K; ++i) {
        float x = S[i * 64 + lane];
#pragma unroll
        for (int r = 0; r < 8; ++r)
            acc[r] = fmaf(x, Wg[(o0 + r) * ld + i], acc[r]);
    }
}

// ---------------------------------------------------------------------------
// k_fused: per (b, 64-wide k-tile): x1 -> m1 -> m2 -> m3 -> m4/seed.
// ---------------------------------------------------------------------------
struct FusedW {
    const float *m1_w1, *m1_b1, *m1_w2, *m1_b2, *m1_ws, *m1_bs;
    const float *m2_w1, *m2_b1, *m2_w2, *m2_b2, *m2_ws, *m2_bs;
    const float *m3_w1, *m3_b1, *m3_w2, *m3_b2, *m3_ws, *m3_bs;
    const float *m4_w1, *m4_b1, *m4_w2, *m4_b2;
};

__global__ void __launch_bounds__(512)
k_fused(FusedW P, const float* __restrict__ ws, float* __restrict__ fout) {
    int b  = blockIdx.x >> 2;
    int k0 = (blockIdx.x & 3) * 64;
    int lane = threadIdx.x & 63;
    int wave = __builtin_amdgcn_readfirstlane(threadIdx.x >> 6);

    const float* T1  = ws;
    const float* T1s = ws + 8192;
    const float* T3  = ws + 16384;
    const float* T3s = ws + 24576;
    float* stage = fout + X3_OFF + b * 32768;

    __shared__ float Xs[8192];
    __shared__ float Hs[8192];

#pragma unroll
    for (int s = 0; s < 16; ++s) {
        int e = threadIdx.x + s * 512;
        int o = e >> 6, kk = e & 63;
        Xs[e] = stage[o * 256 + k0 + kk];
    }
    __syncthreads();

    float yreg[2][8];

    // ================= m1 =================
#pragma unroll
    for (int half = 0; half < 2; ++half) {
        int o0 = wave * 16 + half * 8;
        float acc[8];
#pragma unroll
        for (int r = 0; r < 8; ++r) acc[r] = T1[(o0 + r) * 64 + b] + P.m1_b1[o0 + r];
        gemm8(P.m1_w1, 640, o0, Xs, 128, acc, lane);
#pragma unroll
        for (int r = 0; r < 8; ++r) Hs[(o0 + r) * 64 + lane] = fmaxf(acc[r], 0.f);
    }
    __syncthreads();
#pragma unroll
    for (int half = 0; half < 2; ++half) {
        int o0 = wave * 16 + half * 8;
        float acc[8];
#pragma unroll
        for (int r = 0; r < 8; ++r)
            acc[r] = T1s[(o0 + r) * 64 + b] + P.m1_b2[o0 + r] + P.m1_bs[o0 + r];
        gemm8(P.m1_w2, 128, o0, Hs, 128, acc, lane);
        gemm8(P.m1_ws, 640, o0, Xs, 128, acc, lane);
#pragma unroll
        for (int r = 0; r < 8; ++r) yreg[half][r] = acc[r];
    }
    __syncthreads();
#pragma unroll
    for (int half = 0; half < 2; ++half) {
        int o0 = wave * 16 + half * 8;
#pragma unroll
        for (int r = 0; r < 8; ++r) Xs[(o0 + r) * 64 + lane] = yreg[half][r];
    }
    __syncthreads();

    // ================= m2 =================
    {
        int o0 = wave * 8;
        float acc[8];
#pragma unroll
        for (int r = 0; r < 8; ++r) acc[r] = P.m2_b1[o0 + r];
        gemm8(P.m2_w1, 128, o0, Xs, 128, acc, lane);
#pragma unroll
        for (int r = 0; r < 8; ++r) Hs[(o0 + r) * 64 + lane] = fmaxf(acc[r], 0.f);
    }
    __syncthreads();
#pragma unroll
    for (int half = 0; half < 2; ++half) {
        int o0 = wave * 16 + half * 8;
        float acc[8];
#pragma unroll
        for (int r = 0; r < 8; ++r) acc[r] = P.m2_b2[o0 + r] + P.m2_bs[o0 + r];
        gemm8(P.m2_w2, 64, o0, Hs, 64, acc, lane);
        gemm8(P.m2_ws, 128, o0, Xs, 128, acc, lane);
#pragma unroll
        for (int r = 0; r < 8; ++r) yreg[half][r] = acc[r];
    }
    __syncthreads();
#pragma unroll
    for (int half = 0; half < 2; ++half) {
        int o0 = wave * 16 + half * 8;
#pragma unroll
        for (int r = 0; r < 8; ++r) Xs[(o0 + r) * 64 + lane] = yreg[half][r];
    }
    __syncthreads();

    // ================= m3 =================
#pragma unroll
    for (int half = 0; half < 2; ++half) {
        int o0 = wave * 16 + half * 8;
        float acc[8];
#pragma unroll
        for (int r = 0; r < 8; ++r) acc[r] = T3[(o0 + r) * 64 + b] + P.m3_b1[o0 + r];
        gemm8(P.m3_w1, 640, o0, Xs, 128, acc, lane);
#pragma unroll
        for (int r = 0; r < 8; ++r) Hs[(o0 + r) * 64 + lane] = fmaxf(acc[r], 0.f);
    }
    __syncthreads();
#pragma unroll
    for (int half = 0; half < 2; ++half) {
        int o0 = wave * 16 + half * 8;
        float acc[8];
#pragma unroll
        for (int r = 0; r < 8; ++r)
            acc[r] = T3s[(o0 + r) * 64 + b] + P.m3_b2[o0 + r] + P.m3_bs[o0 + r];
        gemm8(P.m3_w2, 128, o0, Hs, 128, acc, lane);
        gemm8(P.m3_ws, 640, o0, Xs, 128, acc, lane);
#pragma unroll
        for (int r = 0; r < 8; ++r) yreg[half][r] = acc[r];
    }
    __syncthreads();
#pragma unroll
    for (int half = 0; half < 2; ++half) {
        int o0 = wave * 16 + half * 8;
#pragma unroll
        for (int r = 0; r < 8; ++r) {
            Xs[(o0 + r) * 64 + lane] = yreg[half][r];
            stage[(o0 + r) * 256 + k0 + lane] = yreg[half][r];
        }
    }
    __syncthreads();

    // ================= m4 / seed =================
    {
        int o0 = wave * 8;
        float acc[8];
#pragma unroll
        for (int r = 0; r < 8; ++r) acc[r] = P.m4_b1[o0 + r];
        gemm8(P.m4_w1, 128, o0, Xs, 128, acc, lane);
#pragma unroll
        for (int r = 0; r < 8; ++r) Hs[(o0 + r) * 64 + lane] = fmaxf(acc[r], 0.f);
    }
    __syncthreads();
    if (wave < 3) {
        int d = wave;
        float s = P.m4_b2[d];
        for (int j = 0; j < 64; ++j)
            s = fmaf(Hs[j * 64 + lane], P.m4_w2[d * 64 + j], s);
        fout[b * 768 + d * 256 + k0 + lane] = s;
    }
}

// ---------------------------------------------------------------------------
// DPP wave-64 reductions (canonical GCN pattern: row_shr 1/2/4/8 +
// row_bcast15 (rows 1,3) + row_bcast31 (rows 2,3)); result in lane 63.
// Identity-old makes masked/invalid lanes no-ops.  (v4-proven: fuse to
// v_max_u32_dpp / v_min_u32_dpp — 1 instr per step.)
// ---------------------------------------------------------------------------
__device__ __forceinline__ unsigned wave_max_u32_l63(unsigned v) {
    unsigned t;
    t = (unsigned)__builtin_amdgcn_update_dpp(0, (int)v, 0x111, 0xf, 0xf, false); v = t > v ? t : v;
    t = (unsigned)__builtin_amdgcn_update_dpp(0, (int)v, 0x112, 0xf, 0xf, false); v = t > v ? t : v;
    t = (unsigned)__builtin_amdgcn_update_dpp(0, (int)v, 0x114, 0xf, 0xf, false); v = t > v ? t : v;
    t = (unsigned)__builtin_amdgcn_update_dpp(0, (int)v, 0x118, 0xf, 0xf, false); v = t > v ? t : v;
    t = (unsigned)__builtin_amdgcn_update_dpp(0, (int)v, 0x142, 0xa, 0xf, false); v = t > v ? t : v;
    t = (unsigned)__builtin_amdgcn_update_dpp(0, (int)v, 0x143, 0xc, 0xf, false); v = t > v ? t : v;
    return v;
}
__device__ __forceinline__ unsigned wave_min_u32_l63(unsigned v) {
    unsigned t;
    t = (unsigned)__builtin_amdgcn_update_dpp(-1, (int)v, 0x111, 0xf, 0xf, false); v = t < v ? t : v;
    t = (unsigned)__builtin_amdgcn_update_dpp(-1, (int)v, 0x112, 0xf, 0xf, false); v = t < v ? t : v;
    t = (unsigned)__builtin_amdgcn_update_dpp(-1, (int)v, 0x114, 0xf, 0xf, false); v = t < v ? t : v;
    t = (unsigned)__builtin_amdgcn_update_dpp(-1, (int)v, 0x118, 0xf, 0xf, false); v = t < v ? t : v;
    t = (unsigned)__builtin_amdgcn_update_dpp(-1, (int)v, 0x142, 0xa, 0xf, false); v = t < v ? t : v;
    t = (unsigned)__builtin_amdgcn_update_dpp(-1, (int)v, 0x143, 0xc, 0xf, false); v = t < v ? t : v;
    return v;
}

__device__ __forceinline__ unsigned umin_u(unsigned a, unsigned b) { return a < b ? a : b; }

// ---------------------------------------------------------------------------
// k_fps (v10 = v4 + tree select ONLY — isolating v8's tree component).
// v8 = tree + candxyz-prefetch regressed (+33us); theory: prefetch's
// dependent LDS rw on the pre-barrier critical path was the cost, tree
// itself is a depth win (17-step serial chain depth ~34 -> max3/min3 trees
// depth ~6, same instruction count).  Everything else byte-identical to v4:
// dist arithmetic, fused-u32 2-phase DPP, cand write, barrier, u64 merge,
// pts[bi] broadcast read.
// Exactness: fmaxf returns an input bit-exactly (dist>=0, no NaN); m is one
// of dist[s]; min s among dist[s]==m == first-index argmax tie semantics.
// ---------------------------------------------------------------------------
__global__ void __launch_bounds__(256)
k_fps(const float* __restrict__ seed, const float* __restrict__ partial,
      float* __restrict__ outx) {
    int b = blockIdx.x;
    int tid = threadIdx.x;        // 0..255
    int lane = tid & 63;
    int wv = tid >> 6;            // 0..3

    __shared__ float pts[4352 * 3];          // [idx][3]
    __shared__ unsigned long long cand[2][4];
    __shared__ int fars[512];

    // stage seed [b][3][256] -> pts[idx<256]
    pts[tid * 3 + 0] = seed[b * 768 + tid];
    pts[tid * 3 + 1] = seed[b * 768 + 256 + tid];
    pts[tid * 3 + 2] = seed[b * 768 + 512 + tid];
    // stage partial [b][4096][3] -> pts[256..4351]  (linear 12288 dwords)
#pragma unroll
    for (int j = 0; j < 48; ++j) {
        int e = tid + j * 256;
        pts[768 + e] = partial[b * 12288 + e];
    }
    if (tid == 0) fars[0] = 0;
    __syncthreads();

    float px[17], py[17], pz[17], dist[17];
#pragma unroll
    for (int s = 0; s < 17; ++s) {
        int g = s * 256 + tid;
        px[s] = pts[g * 3 + 0];
        py[s] = pts[g * 3 + 1];
        pz[s] = pts[g * 3 + 2];
        dist[s] = 1e10f;
    }
    float cx = pts[0], cy = pts[1], cz = pts[2];

    for (int t = 0; t < 511; ++t) {
        // ---- parallel phase: min-dist update (bit-exact vs reference) ----
#pragma unroll
        for (int s = 0; s < 17; ++s) {
            float dx = px[s] - cx, dy = py[s] - cy, dz = pz[s] - cz;
            float d = __fadd_rn(__fadd_rn(__fmul_rn(dx, dx), __fmul_rn(dy, dy)),
                                __fmul_rn(dz, dz));
            dist[s] = fminf(dist[s], d);
        }
        // ---- thread-local max: max3 tree (depth 3), no index carried ----
        float a0 = fmaxf(fmaxf(dist[0], dist[1]), dist[2]);
        float a1 = fmaxf(fmaxf(dist[3], dist[4]), dist[5]);
        float a2 = fmaxf(fmaxf(dist[6], dist[7]), dist[8]);
        float a3 = fmaxf(fmaxf(dist[9], dist[10]), dist[11]);
        float a4 = fmaxf(fmaxf(dist[12], dist[13]), dist[14]);
        float a5 = fmaxf(dist[15], dist[16]);
        float b0 = fmaxf(fmaxf(a0, a1), a2);
        float b1 = fmaxf(fmaxf(a3, a4), a5);
        float m  = fmaxf(b0, b1);
        // ---- index recovery: min s with dist[s]==m (parallel eq + min3) --
        unsigned e[17];
#pragma unroll
        for (int s = 0; s < 17; ++s)
            e[s] = (dist[s] == m) ? (unsigned)s : 63u;
        unsigned c0 = umin_u(umin_u(e[0], e[1]), e[2]);
        unsigned c1 = umin_u(umin_u(e[3], e[4]), e[5]);
        unsigned c2 = umin_u(umin_u(e[6], e[7]), e[8]);
        unsigned c3 = umin_u(umin_u(e[9], e[10]), e[11]);
        unsigned c4 = umin_u(umin_u(e[12], e[13]), e[14]);
        unsigned c5 = umin_u(e[15], e[16]);
        unsigned d0 = umin_u(umin_u(c0, c1), c2);
        unsigned d1 = umin_u(umin_u(c3, c4), c5);
        unsigned sm = umin_u(d0, d1);
        unsigned bg = (sm << 8) + (unsigned)tid;    // gidx = s*256 + tid

        // phase 1: wave max of dist bits (dist >= 0 so u32 order == f32 order)
        unsigned mv = wave_max_u32_l63(__float_as_uint(m));
        unsigned maxbits = (unsigned)__builtin_amdgcn_readlane((int)mv, 63);
        // phase 2: wave min of candidate global index among exact-max ties
        unsigned cg = (__float_as_uint(m) == maxbits) ? bg : 0xFFFFFFFFu;
        unsigned mgv = wave_min_u32_l63(cg);
        unsigned big = (unsigned)__builtin_amdgcn_readlane((int)mgv, 63);

        if (lane == 0)
            cand[t & 1][wv] = (((unsigned long long)maxbits) << 32) |
                              (unsigned long long)(8191u - big);
        __syncthreads();
        unsigned long long U0 = cand[t & 1][0];
        unsigned long long U1 = cand[t & 1][1];
        unsigned long long U2 = cand[t & 1][2];
        unsigned long long U3 = cand[t & 1][3];
        if (U1 > U0) U0 = U1;
        if (U3 > U2) U2 = U3;
        if (U2 > U0) U0 = U2;
        int bi = 8191 - (int)(U0 & 8191ull);
        cx = pts[bi * 3 + 0]; cy = pts[bi * 3 + 1]; cz = pts[bi * 3 + 2];
        if (tid == 0) fars[t + 1] = bi;
    }
    __syncthreads();

    // gather outputs: x [b][3][512]
#pragma unroll
    for (int j = 0; j < 2; ++j) {
        int n = tid + j * 256;
        int idx = fars[n];
        int ob = b * 1536 + n;
        outx[ob]        = pts[idx * 3 + 0];
        outx[ob + 512]  = pts[idx * 3 + 1];
        outx[ob + 1024] = pts[idx * 3 + 2];
    }
}

// ---------------------------------------------------------------------------
extern "C" void kernel_launch(void* const* d_in, const int* in_sizes, int n_in,
                              void* d_out, int out_size, void* d_ws, size_t ws_size,
                              hipStream_t stream) {
    (void)in_sizes; (void)n_in; (void)out_size; (void)ws_size;
    const float* feat    = (const float*)d_in[0];
    const float* partial = (const float*)d_in[3];
    const float* psw     = (const float*)d_in[4];
    const float* psb     = (const float*)d_in[5];

    FusedW P;
    P.m1_w1 = (const float*)d_in[6];  P.m1_b1 = (const float*)d_in[7];
    P.m1_w2 = (const float*)d_in[8];  P.m1_b2 = (const float*)d_in[9];
    P.m1_ws = (const float*)d_in[10]; P.m1_bs = (const float*)d_in[11];
    P.m2_w1 = (const float*)d_in[12]; P.m2_b1 = (const float*)d_in[13];
    P.m2_w2 = (const float*)d_in[14]; P.m2_b2 = (const float*)d_in[15];
    P.m2_ws = (const float*)d_in[16]; P.m2_bs = (const float*)d_in[17];
    P.m3_w1 = (const float*)d_in[18]; P.m3_b1 = (const float*)d_in[19];
    P.m3_w2 = (const float*)d_in[20]; P.m3_b2 = (const float*)d_in[21];
    P.m3_ws = (const float*)d_in[22]; P.m3_bs = (const float*)d_in[23];
    P.m4_w1 = (const float*)d_in[24]; P.m4_b1 = (const float*)d_in[25];
    P.m4_w2 = (const float*)d_in[26]; P.m4_b2 = (const float*)d_in[27];

    float* W = (float*)d_ws;
    float* out = (float*)d_out;

    k_prep<<<dim3(128), dim3(256), 0, stream>>>(feat, W);
    k_tterms<<<dim3(128), dim3(256), 0, stream>>>(P.m1_w1, P.m1_ws, P.m3_w1, P.m3_ws, W);
    k_deconv<<<dim3(128, 4), dim3(256), 0, stream>>>(psw, psb, W, out + X3_OFF);
    k_fused<<<dim3(256), dim3(512), 0, stream>>>(P, W, out);
    k_fps<<<dim3(64), dim3(256), 0, stream>>>(out, partial, out + FPS_OFF);
}

// Round 9
// 749.389 us; speedup vs baseline: 1.0468x; 1.0196x over previous
//
#include <hip/hip_runtime.h>
#include <stdint.h>

// d_out (f32) layout: seed [64][3][256] @0, x3 [64][128][256] @49152,
// fps x [64][3][512] @2146304.  x3 region doubles as x1 staging.
#define X3_OFF 49152
#define FPS_OFF 2146304

// ws (f32) layout: T1 @0, T1s @8192, T3 @16384, T3s @24576 (each [128][64]),
// featT [512][64] @32768.  Total 65536 floats = 256 KB.

// ---------------------------------------------------------------------------
// k_prep_tterms (merged): blocks 0..127 do prep (featT[c][b] = feat[b][c]);
// blocks 128..255 do tterms DIRECTLY from feat (no featT dependency:
// feat[b*512+c] reads are 128KB L2-resident; same values, same fma order as
// before -> bit-exact).  Saves one kernel launch + its gap.
// ---------------------------------------------------------------------------
__global__ void k_prep_tterms(const float* __restrict__ feat,
                              const float* __restrict__ w1, const float* __restrict__ ws1,
                              const float* __restrict__ w3, const float* __restrict__ ws3,
                              float* __restrict__ ws) {
    int blk = blockIdx.x;
    if (blk < 128) {
        int g = blk * 256 + threadIdx.x;   // 32768
        int c = g >> 6, b = g & 63;
        ws[32768 + c * 64 + b] = feat[b * 512 + c];
    } else {
        int g = (blk - 128) * 256 + threadIdx.x;   // 32768
        int which = g >> 13;
        int o = (g >> 6) & 127;
        int b = g & 63;
        const float* W = (which == 0) ? w1 : (which == 1) ? ws1
                         : (which == 2) ? w3 : ws3;
        float acc = 0.f;
#pragma unroll 4
        for (int c = 0; c < 512; ++c)
            acc = fmaf(W[o * 640 + 128 + c], feat[b * 512 + c], acc);
        ws[which * 8192 + o * 64 + b] = acc;
    }
}

// ---------------------------------------------------------------------------
// k_deconv v2: x1[b][o][k] = sum_c feat[b][c]*ps_w[c][o][k] + ps_b[o]
// acc[32], y-blocks=2 (was acc[16], y=4).  Arithmetic intensity 16->32
// FMA per psw float: psw fetch 256MB -> 128MB (BW-bound side halves).
// #pragma unroll 2 pins the c-loop unroll so register use stays ~80 VGPR
// (prior acc[32] spill was unbounded unroll).
// ---------------------------------------------------------------------------
__global__ void __launch_bounds__(256)
k_deconv(const float* __restrict__ psw,
         const float* __restrict__ psb,
         const float* __restrict__ ws,
         float* __restrict__ stage) {
    int n = blockIdx.x * 256 + threadIdx.x;   // 32768 = o*256+k
    int b0 = blockIdx.y * 32;
    const float* featT = ws + 32768;
    float acc[32];
    float bias = psb[n >> 8];
#pragma unroll
    for (int j = 0; j < 32; ++j) acc[j] = bias;
#pragma unroll 2
    for (int c = 0; c < 512; ++c) {
        float pw = psw[c * 32768 + n];
#pragma unroll
        for (int j = 0; j < 32; ++j)
            acc[j] = fmaf(pw, featT[c * 64 + b0 + j], acc[j]);
    }
#pragma unroll
    for (int j = 0; j < 32; ++j)
        stage[(b0 + j) * 32768 + n] = acc[j];
}

// ---------------------------------------------------------------------------
// gemm8: acc[r] += sum_i S[i][lane] * Wg[(o0+r)*ld + i]  (o0 wave-uniform)
// ---------------------------------------------------------------------------
__device__ __forceinline__ void gemm8(const float* __restrict__ Wg, int ld, int o0,
                                      const float* S, int K, float acc[8], int lane) {
#pragma unroll 4
    for (int i = 0; i < K; ++i) {
        float x = S[i * 64 + lane];
#pragma unroll
        for (int r = 0; r < 8; ++r)
            acc[r] = fmaf(x, Wg[(o0 + r) * ld + i], acc[r]);
    }
}

// ---------------------------------------------------------------------------
// k_fused: per (b, 64-wide k-tile): x1 -> m1 -> m2 -> m3 -> m4/seed.
// ---------------------------------------------------------------------------
struct FusedW {
    const float *m1_w1, *m1_b1, *m1_w2, *m1_b2, *m1_ws, *m1_bs;
    const float *m2_w1, *m2_b1, *m2_w2, *m2_b2, *m2_ws, *m2_bs;
    const float *m3_w1, *m3_b1, *m3_w2, *m3_b2, *m3_ws, *m3_bs;
    const float *m4_w1, *m4_b1, *m4_w2, *m4_b2;
};

__global__ void __launch_bounds__(512)
k_fused(FusedW P, const float* __restrict__ ws, float* __restrict__ fout) {
    int b  = blockIdx.x >> 2;
    int k0 = (blockIdx.x & 3) * 64;
    int lane = threadIdx.x & 63;
    int wave = __builtin_amdgcn_readfirstlane(threadIdx.x >> 6);

    const float* T1  = ws;
    const float* T1s = ws + 8192;
    const float* T3  = ws + 16384;
    const float* T3s = ws + 24576;
    float* stage = fout + X3_OFF + b * 32768;

    __shared__ float Xs[8192];
    __shared__ float Hs[8192];

#pragma unroll
    for (int s = 0; s < 16; ++s) {
        int e = threadIdx.x + s * 512;
        int o = e >> 6, kk = e & 63;
        Xs[e] = stage[o * 256 + k0 + kk];
    }
    __syncthreads();

    float yreg[2][8];

    // ================= m1 =================
#pragma unroll
    for (int half = 0; half < 2; ++half) {
        int o0 = wave * 16 + half * 8;
        float acc[8];
#pragma unroll
        for (int r = 0; r < 8; ++r) acc[r] = T1[(o0 + r) * 64 + b] + P.m1_b1[o0 + r];
        gemm8(P.m1_w1, 640, o0, Xs, 128, acc, lane);
#pragma unroll
        for (int r = 0; r < 8; ++r) Hs[(o0 + r) * 64 + lane] = fmaxf(acc[r], 0.f);
    }
    __syncthreads();
#pragma unroll
    for (int half = 0; half < 2; ++half) {
        int o0 = wave * 16 + half * 8;
        float acc[8];
#pragma unroll
        for (int r = 0; r < 8; ++r)
            acc[r] = T1s[(o0 + r) * 64 + b] + P.m1_b2[o0 + r] + P.m1_bs[o0 + r];
        gemm8(P.m1_w2, 128, o0, Hs, 128, acc, lane);
        gemm8(P.m1_ws, 640, o0, Xs, 128, acc, lane);
#pragma unroll
        for (int r = 0; r < 8; ++r) yreg[half][r] = acc[r];
    }
    __syncthreads();
#pragma unroll
    for (int half = 0; half < 2; ++half) {
        int o0 = wave * 16 + half * 8;
#pragma unroll
        for (int r = 0; r < 8; ++r) Xs[(o0 + r) * 64 + lane] = yreg[half][r];
    }
    __syncthreads();

    // ================= m2 =================
    {
        int o0 = wave * 8;
        float acc[8];
#pragma unroll
        for (int r = 0; r < 8; ++r) acc[r] = P.m2_b1[o0 + r];
        gemm8(P.m2_w1, 128, o0, Xs, 128, acc, lane);
#pragma unroll
        for (int r = 0; r < 8; ++r) Hs[(o0 + r) * 64 + lane] = fmaxf(acc[r], 0.f);
    }
    __syncthreads();
#pragma unroll
    for (int half = 0; half < 2; ++half) {
        int o0 = wave * 16 + half * 8;
        float acc[8];
#pragma unroll
        for (int r = 0; r < 8; ++r) acc[r] = P.m2_b2[o0 + r] + P.m2_bs[o0 + r];
        gemm8(P.m2_w2, 64, o0, Hs, 64, acc, lane);
        gemm8(P.m2_ws, 128, o0, Xs, 128, acc, lane);
#pragma unroll
        for (int r = 0; r < 8; ++r) yreg[half][r] = acc[r];
    }
    __syncthreads();
#pragma unroll
    for (int half = 0; half < 2; ++half) {
        int o0 = wave * 16 + half * 8;
#pragma unroll
        for (int r = 0; r < 8; ++r) Xs[(o0 + r) * 64 + lane] = yreg[half][r];
    }
    __syncthreads();

    // ================= m3 =================
#pragma unroll
    for (int half = 0; half < 2; ++half) {
        int o0 = wave * 16 + half * 8;
        float acc[8];
#pragma unroll
        for (int r = 0; r < 8; ++r) acc[r] = T3[(o0 + r) * 64 + b] + P.m3_b1[o0 + r];
        gemm8(P.m3_w1, 640, o0, Xs, 128, acc, lane);
#pragma unroll
        for (int r = 0; r < 8; ++r) Hs[(o0 + r) * 64 + lane] = fmaxf(acc[r], 0.f);
    }
    __syncthreads();
#pragma unroll
    for (int half = 0; half < 2; ++half) {
        int o0 = wave * 16 + half * 8;
        float acc[8];
#pragma unroll
        for (int r = 0; r < 8; ++r)
            acc[r] = T3s[(o0 + r) * 64 + b] + P.m3_b2[o0 + r] + P.m3_bs[o0 + r];
        gemm8(P.m3_w2, 128, o0, Hs, 128, acc, lane);
        gemm8(P.m3_ws, 640, o0, Xs, 128, acc, lane);
#pragma unroll
        for (int r = 0; r < 8; ++r) yreg[half][r] = acc[r];
    }
    __syncthreads();
#pragma unroll
    for (int half = 0; half < 2; ++half) {
        int o0 = wave * 16 + half * 8;
#pragma unroll
        for (int r = 0; r < 8; ++r) {
            Xs[(o0 + r) * 64 + lane] = yreg[half][r];
            stage[(o0 + r) * 256 + k0 + lane] = yreg[half][r];
        }
    }
    __syncthreads();

    // ================= m4 / seed =================
    {
        int o0 = wave * 8;
        float acc[8];
#pragma unroll
        for (int r = 0; r < 8; ++r) acc[r] = P.m4_b1[o0 + r];
        gemm8(P.m4_w1, 128, o0, Xs, 128, acc, lane);
#pragma unroll
        for (int r = 0; r < 8; ++r) Hs[(o0 + r) * 64 + lane] = fmaxf(acc[r], 0.f);
    }
    __syncthreads();
    if (wave < 3) {
        int d = wave;
        float s = P.m4_b2[d];
        for (int j = 0; j < 64; ++j)
            s = fmaf(Hs[j * 64 + lane], P.m4_w2[d * 64 + j], s);
        fout[b * 768 + d * 256 + k0 + lane] = s;
    }
}

// ---------------------------------------------------------------------------
// DPP wave-64 reductions (canonical GCN pattern: row_shr 1/2/4/8 +
// row_bcast15 (rows 1,3) + row_bcast31 (rows 2,3)); result in lane 63.
// Identity-old makes masked/invalid lanes no-ops.
// ---------------------------------------------------------------------------
__device__ __forceinline__ unsigned wave_max_u32_l63(unsigned v) {
    unsigned t;
    t = (unsigned)__builtin_amdgcn_update_dpp(0, (int)v, 0x111, 0xf, 0xf, false); v = t > v ? t : v;
    t = (unsigned)__builtin_amdgcn_update_dpp(0, (int)v, 0x112, 0xf, 0xf, false); v = t > v ? t : v;
    t = (unsigned)__builtin_amdgcn_update_dpp(0, (int)v, 0x114, 0xf, 0xf, false); v = t > v ? t : v;
    t = (unsigned)__builtin_amdgcn_update_dpp(0, (int)v, 0x118, 0xf, 0xf, false); v = t > v ? t : v;
    t = (unsigned)__builtin_amdgcn_update_dpp(0, (int)v, 0x142, 0xa, 0xf, false); v = t > v ? t : v;
    t = (unsigned)__builtin_amdgcn_update_dpp(0, (int)v, 0x143, 0xc, 0xf, false); v = t > v ? t : v;
    return v;
}
__device__ __forceinline__ unsigned wave_min_u32_l63(unsigned v) {
    unsigned t;
    t = (unsigned)__builtin_amdgcn_update_dpp(-1, (int)v, 0x111, 0xf, 0xf, false); v = t < v ? t : v;
    t = (unsigned)__builtin_amdgcn_update_dpp(-1, (int)v, 0x112, 0xf, 0xf, false); v = t < v ? t : v;
    t = (unsigned)__builtin_amdgcn_update_dpp(-1, (int)v, 0x114, 0xf, 0xf, false); v = t < v ? t : v;
    t = (unsigned)__builtin_amdgcn_update_dpp(-1, (int)v, 0x118, 0xf, 0xf, false); v = t < v ? t : v;
    t = (unsigned)__builtin_amdgcn_update_dpp(-1, (int)v, 0x142, 0xa, 0xf, false); v = t < v ? t : v;
    t = (unsigned)__builtin_amdgcn_update_dpp(-1, (int)v, 0x143, 0xc, 0xf, false); v = t < v ? t : v;
    return v;
}

// ---------------------------------------------------------------------------
// k_fps (v4 EXACT — empirical optimum; R3-R8 ladder: v4=309 < v10=317 <
// 512t=331 < v8=342 < v9=345 < v7=421).  One block of 256 threads per batch;
// 4352 pts = 256*17 in registers (dist update) AND mirrored in LDS
// (centroid broadcast + output gather).  Wave reduce: phase-1 DPP max on
// dist bits (u32-monotone, dist>=0) -> readlane63; phase-2 DPP min on
// tie-candidate index -> readlane63.  Exact jnp.argmax tie semantics.
// ---------------------------------------------------------------------------
__global__ void __launch_bounds__(256)
k_fps(const float* __restrict__ seed, const float* __restrict__ partial,
      float* __restrict__ outx) {
    int b = blockIdx.x;
    int tid = threadIdx.x;        // 0..255
    int lane = tid & 63;
    int wv = tid >> 6;            // 0..3

    __shared__ float pts[4352 * 3];          // [idx][3]
    __shared__ unsigned long long cand[2][4];
    __shared__ int fars[512];

    // stage seed [b][3][256] -> pts[idx<256]
    pts[tid * 3 + 0] = seed[b * 768 + tid];
    pts[tid * 3 + 1] = seed[b * 768 + 256 + tid];
    pts[tid * 3 + 2] = seed[b * 768 + 512 + tid];
    // stage partial [b][4096][3] -> pts[256..4351]  (linear 12288 dwords)
#pragma unroll
    for (int j = 0; j < 48; ++j) {
        int e = tid + j * 256;
        pts[768 + e] = partial[b * 12288 + e];
    }
    if (tid == 0) fars[0] = 0;
    __syncthreads();

    float px[17], py[17], pz[17], dist[17];
#pragma unroll
    for (int s = 0; s < 17; ++s) {
        int g = s * 256 + tid;
        px[s] = pts[g * 3 + 0];
        py[s] = pts[g * 3 + 1];
        pz[s] = pts[g * 3 + 2];
        dist[s] = 1e10f;
    }
    float cx = pts[0], cy = pts[1], cz = pts[2];

    for (int t = 0; t < 511; ++t) {
        // update running min-dist; local best (max dist, min gidx first-hit)
        float bv = -1.0f; int bg = 0;
#pragma unroll
        for (int s = 0; s < 17; ++s) {
            float dx = px[s] - cx, dy = py[s] - cy, dz = pz[s] - cz;
            float d = __fadd_rn(__fadd_rn(__fmul_rn(dx, dx), __fmul_rn(dy, dy)),
                                __fmul_rn(dz, dz));
            dist[s] = fminf(dist[s], d);
            if (dist[s] > bv) { bv = dist[s]; bg = s * 256 + tid; }
        }
        // phase 1: wave max of dist bits (dist >= 0 so u32 order == f32 order)
        unsigned mv = wave_max_u32_l63(__float_as_uint(bv));
        unsigned maxbits = (unsigned)__builtin_amdgcn_readlane((int)mv, 63);
        // phase 2: wave min of candidate global index among exact-max ties
        unsigned cg = (__float_as_uint(bv) == maxbits) ? (unsigned)bg : 0xFFFFFFFFu;
        unsigned mgv = wave_min_u32_l63(cg);
        unsigned big = (unsigned)__builtin_amdgcn_readlane((int)mgv, 63);

        if (lane == 0)
            cand[t & 1][wv] = (((unsigned long long)maxbits) << 32) |
                              (unsigned long long)(8191u - big);
        __syncthreads();
        unsigned long long U0 = cand[t & 1][0];
        unsigned long long U1 = cand[t & 1][1];
        unsigned long long U2 = cand[t & 1][2];
        unsigned long long U3 = cand[t & 1][3];
        if (U1 > U0) U0 = U1;
        if (U3 > U2) U2 = U3;
        if (U2 > U0) U0 = U2;
        int bi = 8191 - (int)(U0 & 8191ull);
        cx = pts[bi * 3 + 0]; cy = pts[bi * 3 + 1]; cz = pts[bi * 3 + 2];
        if (tid == 0) fars[t + 1] = bi;
    }
    __syncthreads();

    // gather outputs: x [b][3][512]
#pragma unroll
    for (int j = 0; j < 2; ++j) {
        int n = tid + j * 256;
        int idx = fars[n];
        int ob = b * 1536 + n;
        outx[ob]        = pts[idx * 3 + 0];
        outx[ob + 512]  = pts[idx * 3 + 1];
        outx[ob + 1024] = pts[idx * 3 + 2];
    }
}

// ---------------------------------------------------------------------------
extern "C" void kernel_launch(void* const* d_in, const int* in_sizes, int n_in,
                              void* d_out, int out_size, void* d_ws, size_t ws_size,
                              hipStream_t stream) {
    (void)in_sizes; (void)n_in; (void)out_size; (void)ws_size;
    const float* feat    = (const float*)d_in[0];
    const float* partial = (const float*)d_in[3];
    const float* psw     = (const float*)d_in[4];
    const float* psb     = (const float*)d_in[5];

    FusedW P;
    P.m1_w1 = (const float*)d_in[6];  P.m1_b1 = (const float*)d_in[7];
    P.m1_w2 = (const float*)d_in[8];  P.m1_b2 = (const float*)d_in[9];
    P.m1_ws = (const float*)d_in[10]; P.m1_bs = (const float*)d_in[11];
    P.m2_w1 = (const float*)d_in[12]; P.m2_b1 = (const float*)d_in[13];
    P.m2_w2 = (const float*)d_in[14]; P.m2_b2 = (const float*)d_in[15];
    P.m2_ws = (const float*)d_in[16]; P.m2_bs = (const float*)d_in[17];
    P.m3_w1 = (const float*)d_in[18]; P.m3_b1 = (const float*)d_in[19];
    P.m3_w2 = (const float*)d_in[20]; P.m3_b2 = (const float*)d_in[21];
    P.m3_ws = (const float*)d_in[22]; P.m3_bs = (const float*)d_in[23];
    P.m4_w1 = (const float*)d_in[24]; P.m4_b1 = (const float*)d_in[25];
    P.m4_w2 = (const float*)d_in[26]; P.m4_b2 = (const float*)d_in[27];

    float* W = (float*)d_ws;
    float* out = (float*)d_out;

    k_prep_tterms<<<dim3(256), dim3(256), 0, stream>>>(feat, P.m1_w1, P.m1_ws, P.m3_w1, P.m3_ws, W);
    k_deconv<<<dim3(128, 2), dim3(256), 0, stream>>>(psw, psb, W, out + X3_OFF);
    k_fused<<<dim3(256), dim3(512), 0, stream>>>(P, W, out);
    k_fps<<<dim3(64), dim3(256), 0, stream>>>(out, partial, out + FPS_OFF);
}

// Round 10
// 659.914 us; speedup vs baseline: 1.1888x; 1.1356x over previous
//
#include <hip/hip_runtime.h>
#include <stdint.h>

// d_out (f32) layout: seed [64][3][256] @0, x3 [64][128][256] @49152,
// fps x [64][3][512] @2146304.  x3 region doubles as x1 staging.
#define X3_OFF 49152
#define FPS_OFF 2146304

// ws (f32) layout: T1 @0, T1s @8192, T3 @16384, T3s @24576 (each [128][64]),
// featT [512][64] @32768.  Total 65536 floats = 256 KB.

// ---------------------------------------------------------------------------
// k_prep_tterms (merged, R9-proven): blocks 0..127 prep featT; 128..255
// tterms directly from feat (L2-resident, bit-exact same fma order).
// ---------------------------------------------------------------------------
__global__ void k_prep_tterms(const float* __restrict__ feat,
                              const float* __restrict__ w1, const float* __restrict__ ws1,
                              const float* __restrict__ w3, const float* __restrict__ ws3,
                              float* __restrict__ ws) {
    int blk = blockIdx.x;
    if (blk < 128) {
        int g = blk * 256 + threadIdx.x;   // 32768
        int c = g >> 6, b = g & 63;
        ws[32768 + c * 64 + b] = feat[b * 512 + c];
    } else {
        int g = (blk - 128) * 256 + threadIdx.x;   // 32768
        int which = g >> 13;
        int o = (g >> 6) & 127;
        int b = g & 63;
        const float* W = (which == 0) ? w1 : (which == 1) ? ws1
                         : (which == 2) ? w3 : ws3;
        float acc = 0.f;
#pragma unroll 4
        for (int c = 0; c < 512; ++c)
            acc = fmaf(W[o * 640 + 128 + c], feat[b * 512 + c], acc);
        ws[which * 8192 + o * 64 + b] = acc;
    }
}

// ---------------------------------------------------------------------------
// k_deconv (R6-proven acc[16]/y=4 shape + unroll 8 on c-loop):
// x1[b][o][k] = sum_c feat[b][c]*ps_w[c][o][k] + ps_b[o].
// unroll 8 keeps 8 independent psw global loads in flight -> one vmcnt
// stall per 128 FMAs instead of per 16 (latency-stall theory of the
// 433us residual).
// ---------------------------------------------------------------------------
__global__ void k_deconv(const float* __restrict__ psw,
                         const float* __restrict__ psb,
                         const float* __restrict__ ws,
                         float* __restrict__ stage) {
    int n = blockIdx.x * 256 + threadIdx.x;   // 32768 = o*256+k
    int b0 = blockIdx.y * 16;
    const float* featT = ws + 32768;
    float acc[16];
    float bias = psb[n >> 8];
#pragma unroll
    for (int j = 0; j < 16; ++j) acc[j] = bias;
#pragma unroll 8
    for (int c = 0; c < 512; ++c) {
        float pw = psw[c * 32768 + n];
#pragma unroll
        for (int j = 0; j < 16; ++j)
            acc[j] = fmaf(pw, featT[c * 64 + b0 + j], acc[j]);
    }
#pragma unroll
    for (int j = 0; j < 16; ++j)
        stage[(b0 + j) * 32768 + n] = acc[j];
}

// ---------------------------------------------------------------------------
// gemm8: acc[r] += sum_i S[i][lane] * Wg[(o0+r)*ld + i]  (o0 wave-uniform)
// ---------------------------------------------------------------------------
__device__ __forceinline__ void gemm8(const float* __restrict__ Wg, int ld, int o0,
                                      const float* S, int K, float acc[8], int lane) {
#pragma unroll 4
    for (int i = 0; i < K; ++i) {
        float x = S[i * 64 + lane];
#pragma unroll
        for (int r = 0; r < 8; ++r)
            acc[r] = fmaf(x, Wg[(o0 + r) * ld + i], acc[r]);
    }
}

// ---------------------------------------------------------------------------
// k_fused v2 (16 waves): per (b, 64-wide k-tile): x1 -> m1 -> m2 -> m3 ->
// m4/seed.  1024 threads = 16 waves = 4 waves/SIMD (was 8 waves = 2/SIMD).
// Each wave owns ONE 8-row group (o0 = wave*8) instead of two: per-wave
// serial gemm chain halves, total issue unchanged, latency overlap doubles.
// 64-row phases (m2/m4 hidden) use waves 0..7; others idle through barrier.
// ---------------------------------------------------------------------------
struct FusedW {
    const float *m1_w1, *m1_b1, *m1_w2, *m1_b2, *m1_ws, *m1_bs;
    const float *m2_w1, *m2_b1, *m2_w2, *m2_b2, *m2_ws, *m2_bs;
    const float *m3_w1, *m3_b1, *m3_w2, *m3_b2, *m3_ws, *m3_bs;
    const float *m4_w1, *m4_b1, *m4_w2, *m4_b2;
};

__global__ void __launch_bounds__(1024)
k_fused(FusedW P, const float* __restrict__ ws, float* __restrict__ fout) {
    int b  = blockIdx.x >> 2;
    int k0 = (blockIdx.x & 3) * 64;
    int lane = threadIdx.x & 63;
    int wave = __builtin_amdgcn_readfirstlane(threadIdx.x >> 6);   // 0..15

    const float* T1  = ws;
    const float* T1s = ws + 8192;
    const float* T3  = ws + 16384;
    const float* T3s = ws + 24576;
    float* stage = fout + X3_OFF + b * 32768;

    __shared__ float Xs[8192];
    __shared__ float Hs[8192];

#pragma unroll
    for (int s = 0; s < 8; ++s) {
        int e = threadIdx.x + s * 1024;
        int o = e >> 6, kk = e & 63;
        Xs[e] = stage[o * 256 + k0 + kk];
    }
    __syncthreads();

    int o0 = wave * 8;   // this wave's 8-row group (0..127)
    float yreg[8];

    // ================= m1 =================
    {
        float acc[8];
#pragma unroll
        for (int r = 0; r < 8; ++r) acc[r] = T1[(o0 + r) * 64 + b] + P.m1_b1[o0 + r];
        gemm8(P.m1_w1, 640, o0, Xs, 128, acc, lane);
#pragma unroll
        for (int r = 0; r < 8; ++r) Hs[(o0 + r) * 64 + lane] = fmaxf(acc[r], 0.f);
    }
    __syncthreads();
    {
        float acc[8];
#pragma unroll
        for (int r = 0; r < 8; ++r)
            acc[r] = T1s[(o0 + r) * 64 + b] + P.m1_b2[o0 + r] + P.m1_bs[o0 + r];
        gemm8(P.m1_w2, 128, o0, Hs, 128, acc, lane);
        gemm8(P.m1_ws, 640, o0, Xs, 128, acc, lane);
#pragma unroll
        for (int r = 0; r < 8; ++r) yreg[r] = acc[r];
    }
    __syncthreads();
#pragma unroll
    for (int r = 0; r < 8; ++r) Xs[(o0 + r) * 64 + lane] = yreg[r];
    __syncthreads();

    // ================= m2 =================
    if (wave < 8) {
        float acc[8];
#pragma unroll
        for (int r = 0; r < 8; ++r) acc[r] = P.m2_b1[o0 + r];
        gemm8(P.m2_w1, 128, o0, Xs, 128, acc, lane);
#pragma unroll
        for (int r = 0; r < 8; ++r) Hs[(o0 + r) * 64 + lane] = fmaxf(acc[r], 0.f);
    }
    __syncthreads();
    {
        float acc[8];
#pragma unroll
        for (int r = 0; r < 8; ++r) acc[r] = P.m2_b2[o0 + r] + P.m2_bs[o0 + r];
        gemm8(P.m2_w2, 64, o0, Hs, 64, acc, lane);
        gemm8(P.m2_ws, 128, o0, Xs, 128, acc, lane);
#pragma unroll
        for (int r = 0; r < 8; ++r) yreg[r] = acc[r];
    }
    __syncthreads();
#pragma unroll
    for (int r = 0; r < 8; ++r) Xs[(o0 + r) * 64 + lane] = yreg[r];
    __syncthreads();

    // ================= m3 =================
    {
        float acc[8];
#pragma unroll
        for (int r = 0; r < 8; ++r) acc[r] = T3[(o0 + r) * 64 + b] + P.m3_b1[o0 + r];
        gemm8(P.m3_w1, 640, o0, Xs, 128, acc, lane);
#pragma unroll
        for (int r = 0; r < 8; ++r) Hs[(o0 + r) * 64 + lane] = fmaxf(acc[r], 0.f);
    }
    __syncthreads();
    {
        float acc[8];
#pragma unroll
        for (int r = 0; r < 8; ++r)
            acc[r] = T3s[(o0 + r) * 64 + b] + P.m3_b2[o0 + r] + P.m3_bs[o0 + r];
        gemm8(P.m3_w2, 128, o0, Hs, 128, acc, lane);
        gemm8(P.m3_ws, 640, o0, Xs, 128, acc, lane);
#pragma unroll
        for (int r = 0; r < 8; ++r) yreg[r] = acc[r];
    }
    __syncthreads();
#pragma unroll
    for (int r = 0; r < 8; ++r) {
        Xs[(o0 + r) * 64 + lane] = yreg[r];
        stage[(o0 + r) * 256 + k0 + lane] = yreg[r];
    }
    __syncthreads();

    // ================= m4 / seed =================
    if (wave < 8) {
        float acc[8];
#pragma unroll
        for (int r = 0; r < 8; ++r) acc[r] = P.m4_b1[o0 + r];
        gemm8(P.m4_w1, 128, o0, Xs, 128, acc, lane);
#pragma unroll
        for (int r = 0; r < 8; ++r) Hs[(o0 + r) * 64 + lane] = fmaxf(acc[r], 0.f);
    }
    __syncthreads();
    if (wave < 3) {
        int d = wave;
        float s = P.m4_b2[d];
        for (int j = 0; j < 64; ++j)
            s = fmaf(Hs[j * 64 + lane], P.m4_w2[d * 64 + j], s);
        fout[b * 768 + d * 256 + k0 + lane] = s;
    }
}

// ---------------------------------------------------------------------------
// DPP wave-64 reductions (canonical GCN pattern: row_shr 1/2/4/8 +
// row_bcast15 (rows 1,3) + row_bcast31 (rows 2,3)); result in lane 63.
// Identity-old makes masked/invalid lanes no-ops.
// ---------------------------------------------------------------------------
__device__ __forceinline__ unsigned wave_max_u32_l63(unsigned v) {
    unsigned t;
    t = (unsigned)__builtin_amdgcn_update_dpp(0, (int)v, 0x111, 0xf, 0xf, false); v = t > v ? t : v;
    t = (unsigned)__builtin_amdgcn_update_dpp(0, (int)v, 0x112, 0xf, 0xf, false); v = t > v ? t : v;
    t = (unsigned)__builtin_amdgcn_update_dpp(0, (int)v, 0x114, 0xf, 0xf, false); v = t > v ? t : v;
    t = (unsigned)__builtin_amdgcn_update_dpp(0, (int)v, 0x118, 0xf, 0xf, false); v = t > v ? t : v;
    t = (unsigned)__builtin_amdgcn_update_dpp(0, (int)v, 0x142, 0xa, 0xf, false); v = t > v ? t : v;
    t = (unsigned)__builtin_amdgcn_update_dpp(0, (int)v, 0x143, 0xc, 0xf, false); v = t > v ? t : v;
    return v;
}
__device__ __forceinline__ unsigned wave_min_u32_l63(unsigned v) {
    unsigned t;
    t = (unsigned)__builtin_amdgcn_update_dpp(-1, (int)v, 0x111, 0xf, 0xf, false); v = t < v ? t : v;
    t = (unsigned)__builtin_amdgcn_update_dpp(-1, (int)v, 0x112, 0xf, 0xf, false); v = t < v ? t : v;
    t = (unsigned)__builtin_amdgcn_update_dpp(-1, (int)v, 0x114, 0xf, 0xf, false); v = t < v ? t : v;
    t = (unsigned)__builtin_amdgcn_update_dpp(-1, (int)v, 0x118, 0xf, 0xf, false); v = t < v ? t : v;
    t = (unsigned)__builtin_amdgcn_update_dpp(-1, (int)v, 0x142, 0xa, 0xf, false); v = t < v ? t : v;
    t = (unsigned)__builtin_amdgcn_update_dpp(-1, (int)v, 0x143, 0xc, 0xf, false); v = t < v ? t : v;
    return v;
}

// ---------------------------------------------------------------------------
// k_fps (v4 EXACT — empirical optimum; ladder: v4=309-316 < v10=317 <
// 512t=331 < v8=342 < v9=345 < v7=421).  One block of 256 threads per batch;
// 4352 pts = 256*17 in registers AND mirrored in LDS.  Wave reduce:
// phase-1 DPP max on dist bits -> readlane63; phase-2 DPP min on
// tie-candidate index -> readlane63.  Exact jnp.argmax tie semantics.
// ---------------------------------------------------------------------------
__global__ void __launch_bounds__(256)
k_fps(const float* __restrict__ seed, const float* __restrict__ partial,
      float* __restrict__ outx) {
    int b = blockIdx.x;
    int tid = threadIdx.x;        // 0..255
    int lane = tid & 63;
    int wv = tid >> 6;            // 0..3

    __shared__ float pts[4352 * 3];          // [idx][3]
    __shared__ unsigned long long cand[2][4];
    __shared__ int fars[512];

    // stage seed [b][3][256] -> pts[idx<256]
    pts[tid * 3 + 0] = seed[b * 768 + tid];
    pts[tid * 3 + 1] = seed[b * 768 + 256 + tid];
    pts[tid * 3 + 2] = seed[b * 768 + 512 + tid];
    // stage partial [b][4096][3] -> pts[256..4351]  (linear 12288 dwords)
#pragma unroll
    for (int j = 0; j < 48; ++j) {
        int e = tid + j * 256;
        pts[768 + e] = partial[b * 12288 + e];
    }
    if (tid == 0) fars[0] = 0;
    __syncthreads();

    float px[17], py[17], pz[17], dist[17];
#pragma unroll
    for (int s = 0; s < 17; ++s) {
        int g = s * 256 + tid;
        px[s] = pts[g * 3 + 0];
        py[s] = pts[g * 3 + 1];
        pz[s] = pts[g * 3 + 2];
        dist[s] = 1e10f;
    }
    float cx = pts[0], cy = pts[1], cz = pts[2];

    for (int t = 0; t < 511; ++t) {
        // update running min-dist; local best (max dist, min gidx first-hit)
        float bv = -1.0f; int bg = 0;
#pragma unroll
        for (int s = 0; s < 17; ++s) {
            float dx = px[s] - cx, dy = py[s] - cy, dz = pz[s] - cz;
            float d = __fadd_rn(__fadd_rn(__fmul_rn(dx, dx), __fmul_rn(dy, dy)),
                                __fmul_rn(dz, dz));
            dist[s] = fminf(dist[s], d);
            if (dist[s] > bv) { bv = dist[s]; bg = s * 256 + tid; }
        }
        // phase 1: wave max of dist bits (dist >= 0 so u32 order == f32 order)
        unsigned mv = wave_max_u32_l63(__float_as_uint(bv));
        unsigned maxbits = (unsigned)__builtin_amdgcn_readlane((int)mv, 63);
        // phase 2: wave min of candidate global index among exact-max ties
        unsigned cg = (__float_as_uint(bv) == maxbits) ? (unsigned)bg : 0xFFFFFFFFu;
        unsigned mgv = wave_min_u32_l63(cg);
        unsigned big = (unsigned)__builtin_amdgcn_readlane((int)mgv, 63);

        if (lane == 0)
            cand[t & 1][wv] = (((unsigned long long)maxbits) << 32) |
                              (unsigned long long)(8191u - big);
        __syncthreads();
        unsigned long long U0 = cand[t & 1][0];
        unsigned long long U1 = cand[t & 1][1];
        unsigned long long U2 = cand[t & 1][2];
        unsigned long long U3 = cand[t & 1][3];
        if (U1 > U0) U0 = U1;
        if (U3 > U2) U2 = U3;
        if (U2 > U0) U0 = U2;
        int bi = 8191 - (int)(U0 & 8191ull);
        cx = pts[bi * 3 + 0]; cy = pts[bi * 3 + 1]; cz = pts[bi * 3 + 2];
        if (tid == 0) fars[t + 1] = bi;
    }
    __syncthreads();

    // gather outputs: x [b][3][512]
#pragma unroll
    for (int j = 0; j < 2; ++j) {
        int n = tid + j * 256;
        int idx = fars[n];
        int ob = b * 1536 + n;
        outx[ob]        = pts[idx * 3 + 0];
        outx[ob + 512]  = pts[idx * 3 + 1];
        outx[ob + 1024] = pts[idx * 3 + 2];
    }
}

// ---------------------------------------------------------------------------
extern "C" void kernel_launch(void* const* d_in, const int* in_sizes, int n_in,
                              void* d_out, int out_size, void* d_ws, size_t ws_size,
                              hipStream_t stream) {
    (void)in_sizes; (void)n_in; (void)out_size; (void)ws_size;
    const float* feat    = (const float*)d_in[0];
    const float* partial = (const float*)d_in[3];
    const float* psw     = (const float*)d_in[4];
    const float* psb     = (const float*)d_in[5];

    FusedW P;
    P.m1_w1 = (const float*)d_in[6];  P.m1_b1 = (const float*)d_in[7];
    P.m1_w2 = (const float*)d_in[8];  P.m1_b2 = (const float*)d_in[9];
    P.m1_ws = (const float*)d_in[10]; P.m1_bs = (const float*)d_in[11];
    P.m2_w1 = (const float*)d_in[12]; P.m2_b1 = (const float*)d_in[13];
    P.m2_w2 = (const float*)d_in[14]; P.m2_b2 = (const float*)d_in[15];
    P.m2_ws = (const float*)d_in[16]; P.m2_bs = (const float*)d_in[17];
    P.m3_w1 = (const float*)d_in[18]; P.m3_b1 = (const float*)d_in[19];
    P.m3_w2 = (const float*)d_in[20]; P.m3_b2 = (const float*)d_in[21];
    P.m3_ws = (const float*)d_in[22]; P.m3_bs = (const float*)d_in[23];
    P.m4_w1 = (const float*)d_in[24]; P.m4_b1 = (const float*)d_in[25];
    P.m4_w2 = (const float*)d_in[26]; P.m4_b2 = (const float*)d_in[27];

    float* W = (float*)d_ws;
    float* out = (float*)d_out;

    k_prep_tterms<<<dim3(256), dim3(256), 0, stream>>>(feat, P.m1_w1, P.m1_ws, P.m3_w1, P.m3_ws, W);
    k_deconv<<<dim3(128, 4), dim3(256), 0, stream>>>(psw, psb, W, out + X3_OFF);
    k_fused<<<dim3(256), dim3(1024), 0, stream>>>(P, W, out);
    k_fps<<<dim3(64), dim3(256), 0, stream>>>(out, partial, out + FPS_OFF);
}

// Round 11
// 659.245 us; speedup vs baseline: 1.1900x; 1.0010x over previous
//
#include <hip/hip_runtime.h>
#include <stdint.h>

// d_out (f32) layout: seed [64][3][256] @0, x3 [64][128][256] @49152,
// fps x [64][3][512] @2146304.  x3 region doubles as x1 staging.
#define X3_OFF 49152
#define FPS_OFF 2146304

// ws (f32) layout: T1 @0, T1s @8192, T3 @16384, T3s @24576 (each [128][64]),
// featT [512][64] @32768.  Total 65536 floats = 256 KB.

// ---------------------------------------------------------------------------
// k_prep_tterms (merged, R9-proven): blocks 0..127 prep featT; 128..255
// tterms directly from feat (L2-resident, bit-exact same fma order).
// ---------------------------------------------------------------------------
__global__ void k_prep_tterms(const float* __restrict__ feat,
                              const float* __restrict__ w1, const float* __restrict__ ws1,
                              const float* __restrict__ w3, const float* __restrict__ ws3,
                              float* __restrict__ ws) {
    int blk = blockIdx.x;
    if (blk < 128) {
        int g = blk * 256 + threadIdx.x;   // 32768
        int c = g >> 6, b = g & 63;
        ws[32768 + c * 64 + b] = feat[b * 512 + c];
    } else {
        int g = (blk - 128) * 256 + threadIdx.x;   // 32768
        int which = g >> 13;
        int o = (g >> 6) & 127;
        int b = g & 63;
        const float* W = (which == 0) ? w1 : (which == 1) ? ws1
                         : (which == 2) ? w3 : ws3;
        float acc = 0.f;
#pragma unroll 4
        for (int c = 0; c < 512; ++c)
            acc = fmaf(W[o * 640 + 128 + c], feat[b * 512 + c], acc);
        ws[which * 8192 + o * 64 + b] = acc;
    }
}

// ---------------------------------------------------------------------------
// k_deconv (R10-proven: acc[16]/y=4 + unroll 8 on c-loop):
// x1[b][o][k] = sum_c feat[b][c]*ps_w[c][o][k] + ps_b[o].
// unroll 8 keeps 8 independent psw global loads in flight.
// ---------------------------------------------------------------------------
__global__ void k_deconv(const float* __restrict__ psw,
                         const float* __restrict__ psb,
                         const float* __restrict__ ws,
                         float* __restrict__ stage) {
    int n = blockIdx.x * 256 + threadIdx.x;   // 32768 = o*256+k
    int b0 = blockIdx.y * 16;
    const float* featT = ws + 32768;
    float acc[16];
    float bias = psb[n >> 8];
#pragma unroll
    for (int j = 0; j < 16; ++j) acc[j] = bias;
#pragma unroll 8
    for (int c = 0; c < 512; ++c) {
        float pw = psw[c * 32768 + n];
#pragma unroll
        for (int j = 0; j < 16; ++j)
            acc[j] = fmaf(pw, featT[c * 64 + b0 + j], acc[j]);
    }
#pragma unroll
    for (int j = 0; j < 16; ++j)
        stage[(b0 + j) * 32768 + n] = acc[j];
}

// ---------------------------------------------------------------------------
// gemm8 v2 (float4 weight loads): acc[r] += sum_i S[i][lane]*Wg[(o0+r)*ld+i].
// Was 8 scalar dword loads per 8 FMA (1:1 VMEM:FMA issue); now 8 dwordx4
// per 32 FMA (1:4) and 32-dword independent load batches for latency
// hiding.  Per-acc[r] fma order unchanged (i ascending) -> bit-exact.
// Requires ld%4==0 (640/128/64 ok) and K%4==0 (128/128/64 ok); 16B-aligned
// rows (o0 multiple of 8, base 256B-aligned).
// ---------------------------------------------------------------------------
__device__ __forceinline__ void gemm8(const float* __restrict__ Wg, int ld, int o0,
                                      const float* S, int K, float acc[8], int lane) {
#pragma unroll 2
    for (int i = 0; i < K; i += 4) {
        float4 w[8];
#pragma unroll
        for (int r = 0; r < 8; ++r)
            w[r] = *reinterpret_cast<const float4*>(&Wg[(o0 + r) * ld + i]);
        float x0 = S[(i + 0) * 64 + lane];
        float x1 = S[(i + 1) * 64 + lane];
        float x2 = S[(i + 2) * 64 + lane];
        float x3 = S[(i + 3) * 64 + lane];
#pragma unroll
        for (int r = 0; r < 8; ++r) {
            acc[r] = fmaf(x0, w[r].x, acc[r]);
            acc[r] = fmaf(x1, w[r].y, acc[r]);
            acc[r] = fmaf(x2, w[r].z, acc[r]);
            acc[r] = fmaf(x3, w[r].w, acc[r]);
        }
    }
}

// ---------------------------------------------------------------------------
// k_fused v2 (16 waves, R10-proven): per (b, 64-wide k-tile): x1 -> m1 ->
// m2 -> m3 -> m4/seed.  1024 threads = 16 waves = 4 waves/SIMD; each wave
// owns ONE 8-row group (o0 = wave*8).  m2/m4 use waves 0..7.
// ---------------------------------------------------------------------------
struct FusedW {
    const float *m1_w1, *m1_b1, *m1_w2, *m1_b2, *m1_ws, *m1_bs;
    const float *m2_w1, *m2_b1, *m2_w2, *m2_b2, *m2_ws, *m2_bs;
    const float *m3_w1, *m3_b1, *m3_w2, *m3_b2, *m3_ws, *m3_bs;
    const float *m4_w1, *m4_b1, *m4_w2, *m4_b2;
};

__global__ void __launch_bounds__(1024)
k_fused(FusedW P, const float* __restrict__ ws, float* __restrict__ fout) {
    int b  = blockIdx.x >> 2;
    int k0 = (blockIdx.x & 3) * 64;
    int lane = threadIdx.x & 63;
    int wave = __builtin_amdgcn_readfirstlane(threadIdx.x >> 6);   // 0..15

    const float* T1  = ws;
    const float* T1s = ws + 8192;
    const float* T3  = ws + 16384;
    const float* T3s = ws + 24576;
    float* stage = fout + X3_OFF + b * 32768;

    __shared__ float Xs[8192];
    __shared__ float Hs[8192];

#pragma unroll
    for (int s = 0; s < 8; ++s) {
        int e = threadIdx.x + s * 1024;
        int o = e >> 6, kk = e & 63;
        Xs[e] = stage[o * 256 + k0 + kk];
    }
    __syncthreads();

    int o0 = wave * 8;   // this wave's 8-row group (0..127)
    float yreg[8];

    // ================= m1 =================
    {
        float acc[8];
#pragma unroll
        for (int r = 0; r < 8; ++r) acc[r] = T1[(o0 + r) * 64 + b] + P.m1_b1[o0 + r];
        gemm8(P.m1_w1, 640, o0, Xs, 128, acc, lane);
#pragma unroll
        for (int r = 0; r < 8; ++r) Hs[(o0 + r) * 64 + lane] = fmaxf(acc[r], 0.f);
    }
    __syncthreads();
    {
        float acc[8];
#pragma unroll
        for (int r = 0; r < 8; ++r)
            acc[r] = T1s[(o0 + r) * 64 + b] + P.m1_b2[o0 + r] + P.m1_bs[o0 + r];
        gemm8(P.m1_w2, 128, o0, Hs, 128, acc, lane);
        gemm8(P.m1_ws, 640, o0, Xs, 128, acc, lane);
#pragma unroll
        for (int r = 0; r < 8; ++r) yreg[r] = acc[r];
    }
    __syncthreads();
#pragma unroll
    for (int r = 0; r < 8; ++r) Xs[(o0 + r) * 64 + lane] = yreg[r];
    __syncthreads();

    // ================= m2 =================
    if (wave < 8) {
        float acc[8];
#pragma unroll
        for (int r = 0; r < 8; ++r) acc[r] = P.m2_b1[o0 + r];
        gemm8(P.m2_w1, 128, o0, Xs, 128, acc, lane);
#pragma unroll
        for (int r = 0; r < 8; ++r) Hs[(o0 + r) * 64 + lane] = fmaxf(acc[r], 0.f);
    }
    __syncthreads();
    {
        float acc[8];
#pragma unroll
        for (int r = 0; r < 8; ++r) acc[r] = P.m2_b2[o0 + r] + P.m2_bs[o0 + r];
        gemm8(P.m2_w2, 64, o0, Hs, 64, acc, lane);
        gemm8(P.m2_ws, 128, o0, Xs, 128, acc, lane);
#pragma unroll
        for (int r = 0; r < 8; ++r) yreg[r] = acc[r];
    }
    __syncthreads();
#pragma unroll
    for (int r = 0; r < 8; ++r) Xs[(o0 + r) * 64 + lane] = yreg[r];
    __syncthreads();

    // ================= m3 =================
    {
        float acc[8];
#pragma unroll
        for (int r = 0; r < 8; ++r) acc[r] = T3[(o0 + r) * 64 + b] + P.m3_b1[o0 + r];
        gemm8(P.m3_w1, 640, o0, Xs, 128, acc, lane);
#pragma unroll
        for (int r = 0; r < 8; ++r) Hs[(o0 + r) * 64 + lane] = fmaxf(acc[r], 0.f);
    }
    __syncthreads();
    {
        float acc[8];
#pragma unroll
        for (int r = 0; r < 8; ++r)
            acc[r] = T3s[(o0 + r) * 64 + b] + P.m3_b2[o0 + r] + P.m3_bs[o0 + r];
        gemm8(P.m3_w2, 128, o0, Hs, 128, acc, lane);
        gemm8(P.m3_ws, 640, o0, Xs, 128, acc, lane);
#pragma unroll
        for (int r = 0; r < 8; ++r) yreg[r] = acc[r];
    }
    __syncthreads();
#pragma unroll
    for (int r = 0; r < 8; ++r) {
        Xs[(o0 + r) * 64 + lane] = yreg[r];
        stage[(o0 + r) * 256 + k0 + lane] = yreg[r];
    }
    __syncthreads();

    // ================= m4 / seed =================
    if (wave < 8) {
        float acc[8];
#pragma unroll
        for (int r = 0; r < 8; ++r) acc[r] = P.m4_b1[o0 + r];
        gemm8(P.m4_w1, 128, o0, Xs, 128, acc, lane);
#pragma unroll
        for (int r = 0; r < 8; ++r) Hs[(o0 + r) * 64 + lane] = fmaxf(acc[r], 0.f);
    }
    __syncthreads();
    if (wave < 3) {
        int d = wave;
        float s = P.m4_b2[d];
        for (int j = 0; j < 64; ++j)
            s = fmaf(Hs[j * 64 + lane], P.m4_w2[d * 64 + j], s);
        fout[b * 768 + d * 256 + k0 + lane] = s;
    }
}

// ---------------------------------------------------------------------------
// DPP wave-64 reductions (canonical GCN pattern: row_shr 1/2/4/8 +
// row_bcast15 (rows 1,3) + row_bcast31 (rows 2,3)); result in lane 63.
// Identity-old makes masked/invalid lanes no-ops.
// ---------------------------------------------------------------------------
__device__ __forceinline__ unsigned wave_max_u32_l63(unsigned v) {
    unsigned t;
    t = (unsigned)__builtin_amdgcn_update_dpp(0, (int)v, 0x111, 0xf, 0xf, false); v = t > v ? t : v;
    t = (unsigned)__builtin_amdgcn_update_dpp(0, (int)v, 0x112, 0xf, 0xf, false); v = t > v ? t : v;
    t = (unsigned)__builtin_amdgcn_update_dpp(0, (int)v, 0x114, 0xf, 0xf, false); v = t > v ? t : v;
    t = (unsigned)__builtin_amdgcn_update_dpp(0, (int)v, 0x118, 0xf, 0xf, false); v = t > v ? t : v;
    t = (unsigned)__builtin_amdgcn_update_dpp(0, (int)v, 0x142, 0xa, 0xf, false); v = t > v ? t : v;
    t = (unsigned)__builtin_amdgcn_update_dpp(0, (int)v, 0x143, 0xc, 0xf, false); v = t > v ? t : v;
    return v;
}
__device__ __forceinline__ unsigned wave_min_u32_l63(unsigned v) {
    unsigned t;
    t = (unsigned)__builtin_amdgcn_update_dpp(-1, (int)v, 0x111, 0xf, 0xf, false); v = t < v ? t : v;
    t = (unsigned)__builtin_amdgcn_update_dpp(-1, (int)v, 0x112, 0xf, 0xf, false); v = t < v ? t : v;
    t = (unsigned)__builtin_amdgcn_update_dpp(-1, (int)v, 0x114, 0xf, 0xf, false); v = t < v ? t : v;
    t = (unsigned)__builtin_amdgcn_update_dpp(-1, (int)v, 0x118, 0xf, 0xf, false); v = t < v ? t : v;
    t = (unsigned)__builtin_amdgcn_update_dpp(-1, (int)v, 0x142, 0xa, 0xf, false); v = t < v ? t : v;
    t = (unsigned)__builtin_amdgcn_update_dpp(-1, (int)v, 0x143, 0xc, 0xf, false); v = t < v ? t : v;
    return v;
}

// ---------------------------------------------------------------------------
// k_fps (v4 EXACT — empirical optimum; ladder: v4=309-316 < v10=317 <
// 512t=331 < v8=342 < v9=345 < v7=421).  One block of 256 threads per batch;
// 4352 pts = 256*17 in registers AND mirrored in LDS.  Wave reduce:
// phase-1 DPP max on dist bits -> readlane63; phase-2 DPP min on
// tie-candidate index -> readlane63.  Exact jnp.argmax tie semantics.
// ---------------------------------------------------------------------------
__global__ void __launch_bounds__(256)
k_fps(const float* __restrict__ seed, const float* __restrict__ partial,
      float* __restrict__ outx) {
    int b = blockIdx.x;
    int tid = threadIdx.x;        // 0..255
    int lane = tid & 63;
    int wv = tid >> 6;            // 0..3

    __shared__ float pts[4352 * 3];          // [idx][3]
    __shared__ unsigned long long cand[2][4];
    __shared__ int fars[512];

    // stage seed [b][3][256] -> pts[idx<256]
    pts[tid * 3 + 0] = seed[b * 768 + tid];
    pts[tid * 3 + 1] = seed[b * 768 + 256 + tid];
    pts[tid * 3 + 2] = seed[b * 768 + 512 + tid];
    // stage partial [b][4096][3] -> pts[256..4351]  (linear 12288 dwords)
#pragma unroll
    for (int j = 0; j < 48; ++j) {
        int e = tid + j * 256;
        pts[768 + e] = partial[b * 12288 + e];
    }
    if (tid == 0) fars[0] = 0;
    __syncthreads();

    float px[17], py[17], pz[17], dist[17];
#pragma unroll
    for (int s = 0; s < 17; ++s) {
        int g = s * 256 + tid;
        px[s] = pts[g * 3 + 0];
        py[s] = pts[g * 3 + 1];
        pz[s] = pts[g * 3 + 2];
        dist[s] = 1e10f;
    }
    float cx = pts[0], cy = pts[1], cz = pts[2];

    for (int t = 0; t < 511; ++t) {
        // update running min-dist; local best (max dist, min gidx first-hit)
        float bv = -1.0f; int bg = 0;
#pragma unroll
        for (int s = 0; s < 17; ++s) {
            float dx = px[s] - cx, dy = py[s] - cy, dz = pz[s] - cz;
            float d = __fadd_rn(__fadd_rn(__fmul_rn(dx, dx), __fmul_rn(dy, dy)),
                                __fmul_rn(dz, dz));
            dist[s] = fminf(dist[s], d);
            if (dist[s] > bv) { bv = dist[s]; bg = s * 256 + tid; }
        }
        // phase 1: wave max of dist bits (dist >= 0 so u32 order == f32 order)
        unsigned mv = wave_max_u32_l63(__float_as_uint(bv));
        unsigned maxbits = (unsigned)__builtin_amdgcn_readlane((int)mv, 63);
        // phase 2: wave min of candidate global index among exact-max ties
        unsigned cg = (__float_as_uint(bv) == maxbits) ? (unsigned)bg : 0xFFFFFFFFu;
        unsigned mgv = wave_min_u32_l63(cg);
        unsigned big = (unsigned)__builtin_amdgcn_readlane((int)mgv, 63);

        if (lane == 0)
            cand[t & 1][wv] = (((unsigned long long)maxbits) << 32) |
                              (unsigned long long)(8191u - big);
        __syncthreads();
        unsigned long long U0 = cand[t & 1][0];
        unsigned long long U1 = cand[t & 1][1];
        unsigned long long U2 = cand[t & 1][2];
        unsigned long long U3 = cand[t & 1][3];
        if (U1 > U0) U0 = U1;
        if (U3 > U2) U2 = U3;
        if (U2 > U0) U0 = U2;
        int bi = 8191 - (int)(U0 & 8191ull);
        cx = pts[bi * 3 + 0]; cy = pts[bi * 3 + 1]; cz = pts[bi * 3 + 2];
        if (tid == 0) fars[t + 1] = bi;
    }
    __syncthreads();

    // gather outputs: x [b][3][512]
#pragma unroll
    for (int j = 0; j < 2; ++j) {
        int n = tid + j * 256;
        int idx = fars[n];
        int ob = b * 1536 + n;
        outx[ob]        = pts[idx * 3 + 0];
        outx[ob + 512]  = pts[idx * 3 + 1];
        outx[ob + 1024] = pts[idx * 3 + 2];
    }
}

// ---------------------------------------------------------------------------
extern "C" void kernel_launch(void* const* d_in, const int* in_sizes, int n_in,
                              void* d_out, int out_size, void* d_ws, size_t ws_size,
                              hipStream_t stream) {
    (void)in_sizes; (void)n_in; (void)out_size; (void)ws_size;
    const float* feat    = (const float*)d_in[0];
    const float* partial = (const float*)d_in[3];
    const float* psw     = (const float*)d_in[4];
    const float* psb     = (const float*)d_in[5];

    FusedW P;
    P.m1_w1 = (const float*)d_in[6];  P.m1_b1 = (const float*)d_in[7];
    P.m1_w2 = (const float*)d_in[8];  P.m1_b2 = (const float*)d_in[9];
    P.m1_ws = (const float*)d_in[10]; P.m1_bs = (const float*)d_in[11];
    P.m2_w1 = (const float*)d_in[12]; P.m2_b1 = (const float*)d_in[13];
    P.m2_w2 = (const float*)d_in[14]; P.m2_b2 = (const float*)d_in[15];
    P.m2_ws = (const float*)d_in[16]; P.m2_bs = (const float*)d_in[17];
    P.m3_w1 = (const float*)d_in[18]; P.m3_b1 = (const float*)d_in[19];
    P.m3_w2 = (const float*)d_in[20]; P.m3_b2 = (const float*)d_in[21];
    P.m3_ws = (const float*)d_in[22]; P.m3_bs = (const float*)d_in[23];
    P.m4_w1 = (const float*)d_in[24]; P.m4_b1 = (const float*)d_in[25];
    P.m4_w2 = (const float*)d_in[26]; P.m4_b2 = (const float*)d_in[27];

    float* W = (float*)d_ws;
    float* out = (float*)d_out;

    k_prep_tterms<<<dim3(256), dim3(256), 0, stream>>>(feat, P.m1_w1, P.m1_ws, P.m3_w1, P.m3_ws, W);
    k_deconv<<<dim3(128, 4), dim3(256), 0, stream>>>(psw, psb, W, out + X3_OFF);
    k_fused<<<dim3(256), dim3(1024), 0, stream>>>(P, W, out);
    k_fps<<<dim3(64), dim3(256), 0, stream>>>(out, partial, out + FPS_OFF);
}